// Round 5
// baseline (330.112 us; speedup 1.0000x reference)
//
#include <hip/hip_runtime.h>

// ---------------------------------------------------------------------------
// 2-layer GCN on MI355X.
//   h   = relu( Dinv (A+I) Dinv (z @ W1) + b1 )
//   out =       Dinv (A+I) Dinv (h @ W2) + b2
// R5: fill writes col only (no ew array) -> halves the scattered-write line
// touches that caused 13x write amplification. Aggregate recomputes
// w = dinv[src]*dinv[dst] from the L2-resident dinv table.
// ---------------------------------------------------------------------------

#define N_NODES 50000
#define N_EDGES 800000
#define D_IN    256
#define D_HID   256
#define D_OUT   128

typedef unsigned int uint32;
typedef unsigned short u16;

typedef __attribute__((ext_vector_type(8))) short bf16x8;   // MFMA A/B frag (4 VGPR)
typedef __attribute__((ext_vector_type(4))) float f32x4;    // MFMA C/D frag

__device__ __forceinline__ u16 f2bf_rne(float f) {
    union { float f; uint32 u; } c; c.f = f;
    uint32 u = c.u;
    u += 0x7FFFu + ((u >> 16) & 1u);
    return (u16)(u >> 16);
}
__device__ __forceinline__ float bf_lo(uint32 p) {
    union { uint32 u; float f; } c; c.u = p << 16; return c.f;
}
__device__ __forceinline__ float bf_hi(uint32 p) {
    union { uint32 u; float f; } c; c.u = p & 0xFFFF0000u; return c.f;
}

// ---------------- conversion kernels ----------------

__global__ __launch_bounds__(256) void cvt_bf16_kernel(const float* __restrict__ in,
                                                       u16* __restrict__ out, int n) {
    int i = (blockIdx.x * blockDim.x + threadIdx.x) * 8;
    if (i < n) {
        float4 a = *(const float4*)(in + i);
        float4 b = *(const float4*)(in + i + 4);
        uint4 pk;
        pk.x = (uint32)f2bf_rne(a.x) | ((uint32)f2bf_rne(a.y) << 16);
        pk.y = (uint32)f2bf_rne(a.z) | ((uint32)f2bf_rne(a.w) << 16);
        pk.z = (uint32)f2bf_rne(b.x) | ((uint32)f2bf_rne(b.y) << 16);
        pk.w = (uint32)f2bf_rne(b.z) | ((uint32)f2bf_rne(b.w) << 16);
        *(uint4*)(out + i) = pk;
    }
}

// WT[n][k] = (bf16) W[k][n];  W is [K][N] f32
__global__ __launch_bounds__(256) void wt_kernel(const float* __restrict__ W,
                                                 u16* __restrict__ WT, int K, int N) {
    int idx = blockIdx.x * 256 + threadIdx.x;
    if (idx < K * N) {
        int nrow = idx / K;
        int kcol = idx - nrow * K;
        WT[idx] = f2bf_rne(W[(size_t)kcol * N + nrow]);
    }
}

// ---------------- CSR build ----------------

__global__ void degree_kernel(const int* __restrict__ dst, int* __restrict__ cnt, int n_edges) {
    int i = blockIdx.x * blockDim.x + threadIdx.x;
    if (i < n_edges) atomicAdd(&cnt[dst[i]], 1);
}

__global__ void dinv_kernel(const int* __restrict__ cnt, float* __restrict__ dinv, int n) {
    int i = blockIdx.x * blockDim.x + threadIdx.x;
    if (i < n) dinv[i] = rsqrtf((float)(cnt[i] + 1));
}

__global__ __launch_bounds__(256) void block_sum_kernel(const int* __restrict__ cnt,
                                                        int* __restrict__ bsum, int n) {
    int b = blockIdx.x, t = threadIdx.x;
    int i = b * 256 + t;
    int v = (i < n) ? cnt[i] : 0;
    #pragma unroll
    for (int off = 32; off >= 1; off >>= 1) v += __shfl_down(v, off, 64);
    __shared__ int ws[4];
    if ((t & 63) == 0) ws[t >> 6] = v;
    __syncthreads();
    if (t == 0) bsum[b] = ws[0] + ws[1] + ws[2] + ws[3];
}

__global__ __launch_bounds__(256) void scan_partials_kernel(const int* __restrict__ bsum,
                                                            int* __restrict__ boff,
                                                            int* __restrict__ row_ptr,
                                                            int nb, int n) {
    int t = threadIdx.x;
    int v = (t < nb) ? bsum[t] : 0;
    int lane = t & 63, w = t >> 6;
    int x = v;
    #pragma unroll
    for (int off = 1; off < 64; off <<= 1) {
        int u = __shfl_up(x, off, 64);
        if (lane >= off) x += u;
    }
    __shared__ int ws[4];
    if (lane == 63) ws[w] = x;
    __syncthreads();
    int base = 0;
    for (int i = 0; i < w; ++i) base += ws[i];
    int incl = base + x;
    if (t < nb) boff[t] = incl - v;
    if (t == 255) row_ptr[n] = incl;
}

__global__ __launch_bounds__(256) void scan_write_kernel(const int* __restrict__ cnt,
                                                         const int* __restrict__ boff,
                                                         int* __restrict__ row_ptr,
                                                         int* __restrict__ cursor, int n) {
    int b = blockIdx.x, t = threadIdx.x;
    int i = b * 256 + t;
    int v = (i < n) ? cnt[i] : 0;
    int lane = t & 63, w = t >> 6;
    int x = v;
    #pragma unroll
    for (int off = 1; off < 64; off <<= 1) {
        int u = __shfl_up(x, off, 64);
        if (lane >= off) x += u;
    }
    __shared__ int ws[4];
    if (lane == 63) ws[w] = x;
    __syncthreads();
    int base = boff[b];
    for (int i2 = 0; i2 < w; ++i2) base += ws[i2];
    int excl = base + (x - v);
    if (i < n) { row_ptr[i] = excl; cursor[i] = excl; }
}

// fill: single 4B scattered write per edge (col index only)
__global__ void fill_kernel(const int* __restrict__ src, const int* __restrict__ dst,
                            int* __restrict__ cursor, int* __restrict__ col, int n_edges) {
    int i = blockIdx.x * blockDim.x + threadIdx.x;
    if (i < n_edges) {
        int d = dst[i];
        int s = src[i];
        int pos = atomicAdd(&cursor[d], 1);
        col[pos] = s;
    }
}

// ---------------- bf16 MFMA GEMM ----------------
// C[M x NT](bf16) = A[M x 256](bf16) * BT[NT x 256](bf16)^T
// Block: 128x128, 256 threads = 4 waves 2x2; BK=32; global_load_lds width=16.

template <int NT>
__global__ __launch_bounds__(256, 4) void gemm_bf16_kernel(const u16* __restrict__ A,
                                                           const u16* __restrict__ BT,
                                                           u16* __restrict__ C, int M) {
    const int K = 256;
    __shared__ short As[128 * 32];   // [m][k]
    __shared__ short Bs[128 * 32];   // [n][k]

    const int m0 = blockIdx.x * 128;
    const int n0 = blockIdx.y * 128;
    const int t  = threadIdx.x;
    const int w  = t >> 6;
    const int lane = t & 63;
    const int lm = lane & 15;
    const int lq = lane >> 4;
    const int wm = w & 1;
    const int wn = w >> 1;

    f32x4 acc[4][4] = {};

    for (int k0 = 0; k0 < K; k0 += 32) {
        #pragma unroll
        for (int j = 0; j < 2; ++j) {
            int c = w * 128 + j * 64 + lane;
            int row = c >> 2;
            int kc = k0 + (c & 3) * 8;
            int gm = m0 + row; if (gm >= M) gm = M - 1;
            const u16* gpa = A  + (size_t)gm * K + kc;
            const u16* gpb = BT + (size_t)(n0 + row) * K + kc;
            __builtin_amdgcn_global_load_lds(
                (const __attribute__((address_space(1))) void*)gpa,
                (__attribute__((address_space(3))) void*)(As + (w * 128 + j * 64) * 8),
                16, 0, 0);
            __builtin_amdgcn_global_load_lds(
                (const __attribute__((address_space(1))) void*)gpb,
                (__attribute__((address_space(3))) void*)(Bs + (w * 128 + j * 64) * 8),
                16, 0, 0);
        }
        __syncthreads();

        bf16x8 af[4], bf[4];
        #pragma unroll
        for (int mt = 0; mt < 4; ++mt)
            af[mt] = *(const bf16x8*)&As[(wm * 64 + mt * 16 + lm) * 32 + lq * 8];
        #pragma unroll
        for (int nt = 0; nt < 4; ++nt)
            bf[nt] = *(const bf16x8*)&Bs[(wn * 64 + nt * 16 + lm) * 32 + lq * 8];

        #pragma unroll
        for (int mt = 0; mt < 4; ++mt)
            #pragma unroll
            for (int nt = 0; nt < 4; ++nt)
                acc[mt][nt] = __builtin_amdgcn_mfma_f32_16x16x32_bf16(
                    af[mt], bf[nt], acc[mt][nt], 0, 0, 0);

        __syncthreads();
    }

    #pragma unroll
    for (int mt = 0; mt < 4; ++mt) {
        #pragma unroll
        for (int r = 0; r < 4; ++r) {
            int gm = m0 + wm * 64 + mt * 16 + lq * 4 + r;
            if (gm < M) {
                #pragma unroll
                for (int nt = 0; nt < 4; ++nt) {
                    int gn = n0 + wn * 64 + nt * 16 + lm;
                    C[(size_t)gm * NT + gn] = f2bf_rne(acc[mt][nt][r]);
                }
            }
        }
    }
}

// ---------------- Aggregation: one wave per node, bf16 gather over CSR ----------------

template <int D, bool RELU, bool OUTBF>
__global__ __launch_bounds__(256) void aggregate_kernel(const u16* __restrict__ x,
                                                        const int* __restrict__ row_ptr,
                                                        const int* __restrict__ col,
                                                        const float* __restrict__ dinv,
                                                        const float* __restrict__ bias,
                                                        void* __restrict__ outp, int n_nodes) {
    constexpr int VPL = D / 64;
    int wave = (blockIdx.x * blockDim.x + threadIdx.x) >> 6;
    int lane = threadIdx.x & 63;
    if (wave >= n_nodes) return;
    const int node = wave;
    const int c0 = lane * VPL;

    float di = dinv[node];
    float acc[4][VPL] = {};

    {   // self-loop: x[node] * dinv^2
        float w = di * di;
        const u16* xs = x + (size_t)node * D + c0;
        if constexpr (VPL == 4) {
            uint2 p = *(const uint2*)xs;
            acc[0][0] = bf_lo(p.x) * w;
            acc[0][1] = bf_hi(p.x) * w;
            acc[0][2] = bf_lo(p.y) * w;
            acc[0][3] = bf_hi(p.y) * w;
        } else {
            uint32 p = *(const uint32*)xs;
            acc[0][0] = bf_lo(p) * w;
            acc[0][1] = bf_hi(p) * w;
        }
    }

    int e0 = row_ptr[node], e1 = row_ptr[node + 1];
    int e = e0;
    for (; e + 4 <= e1; e += 4) {
        #pragma unroll
        for (int u = 0; u < 4; ++u) {
            int s  = col[e + u];
            float w = dinv[s] * di;
            const u16* xs = x + (size_t)s * D + c0;
            if constexpr (VPL == 4) {
                uint2 p = *(const uint2*)xs;
                acc[u][0] = fmaf(bf_lo(p.x), w, acc[u][0]);
                acc[u][1] = fmaf(bf_hi(p.x), w, acc[u][1]);
                acc[u][2] = fmaf(bf_lo(p.y), w, acc[u][2]);
                acc[u][3] = fmaf(bf_hi(p.y), w, acc[u][3]);
            } else {
                uint32 p = *(const uint32*)xs;
                acc[u][0] = fmaf(bf_lo(p), w, acc[u][0]);
                acc[u][1] = fmaf(bf_hi(p), w, acc[u][1]);
            }
        }
    }
    for (; e < e1; ++e) {
        int s  = col[e];
        float w = dinv[s] * di;
        const u16* xs = x + (size_t)s * D + c0;
        if constexpr (VPL == 4) {
            uint2 p = *(const uint2*)xs;
            acc[0][0] = fmaf(bf_lo(p.x), w, acc[0][0]);
            acc[0][1] = fmaf(bf_hi(p.x), w, acc[0][1]);
            acc[0][2] = fmaf(bf_lo(p.y), w, acc[0][2]);
            acc[0][3] = fmaf(bf_hi(p.y), w, acc[0][3]);
        } else {
            uint32 p = *(const uint32*)xs;
            acc[0][0] = fmaf(bf_lo(p), w, acc[0][0]);
            acc[0][1] = fmaf(bf_hi(p), w, acc[0][1]);
        }
    }

    float v[VPL];
    #pragma unroll
    for (int j = 0; j < VPL; ++j) {
        float s = acc[0][j] + acc[1][j] + acc[2][j] + acc[3][j] + bias[c0 + j];
        v[j] = RELU ? fmaxf(s, 0.0f) : s;
    }

    if constexpr (OUTBF) {
        u16* op = (u16*)outp + (size_t)node * D + c0;
        if constexpr (VPL == 4) {
            uint2 pk;
            pk.x = (uint32)f2bf_rne(v[0]) | ((uint32)f2bf_rne(v[1]) << 16);
            pk.y = (uint32)f2bf_rne(v[2]) | ((uint32)f2bf_rne(v[3]) << 16);
            *(uint2*)op = pk;
        } else {
            *(uint32*)op = (uint32)f2bf_rne(v[0]) | ((uint32)f2bf_rne(v[1]) << 16);
        }
    } else {
        float* op = (float*)outp + (size_t)node * D + c0;
        #pragma unroll
        for (int j = 0; j < VPL; ++j) op[j] = v[j];
    }
}

// ---------------- launcher ----------------

extern "C" void kernel_launch(void* const* d_in, const int* in_sizes, int n_in,
                              void* d_out, int out_size, void* d_ws, size_t ws_size,
                              hipStream_t stream) {
    const float* z  = (const float*)d_in[0];
    const int*   ei = (const int*)d_in[1];
    const float* W1 = (const float*)d_in[2];
    const float* b1 = (const float*)d_in[3];
    const float* W2 = (const float*)d_in[4];
    const float* b2 = (const float*)d_in[5];
    float* out = (float*)d_out;

    const int Nn = N_NODES, E = N_EDGES;
    const int* srcp = ei;
    const int* dstp = ei + E;

    char* ws = (char*)d_ws;
    size_t off = 0;
    auto alloc = [&](size_t bytes) -> char* {
        char* p = ws + off;
        off += (bytes + 511) & ~(size_t)511;
        return p;
    };
    u16*   zb     = (u16*)  alloc((size_t)Nn * D_IN * 2);
    u16*   w1t    = (u16*)  alloc((size_t)D_IN * D_HID * 2);
    u16*   w2t    = (u16*)  alloc((size_t)D_HID * D_OUT * 2);
    u16*   x1b    = (u16*)  alloc((size_t)Nn * D_HID * 2);
    u16*   hb     = (u16*)  alloc((size_t)Nn * D_HID * 2);
    u16*   h2b    = (u16*)  alloc((size_t)Nn * D_OUT * 2);
    int*   cnt    = (int*)  alloc((size_t)Nn * 4);
    float* dinv   = (float*)alloc((size_t)Nn * 4);
    int*   row_ptr= (int*)  alloc((size_t)(Nn + 1) * 4);
    int*   cursor = (int*)  alloc((size_t)Nn * 4);
    int*   col    = (int*)  alloc((size_t)E * 4);
    int*   bsum   = (int*)  alloc(256 * 4);
    int*   boff   = (int*)  alloc(256 * 4);

    const int nb = (Nn + 255) / 256;

    // ---- conversions ----
    cvt_bf16_kernel<<<(Nn * D_IN / 8 + 255) / 256, 256, 0, stream>>>(z, zb, Nn * D_IN);
    wt_kernel<<<(D_IN * D_HID + 255) / 256, 256, 0, stream>>>(W1, w1t, D_IN, D_HID);
    wt_kernel<<<(D_HID * D_OUT + 255) / 256, 256, 0, stream>>>(W2, w2t, D_HID, D_OUT);

    // ---- CSR build ----
    hipMemsetAsync(cnt, 0, (size_t)Nn * 4, stream);
    degree_kernel<<<(E + 255) / 256, 256, 0, stream>>>(dstp, cnt, E);
    dinv_kernel<<<(Nn + 255) / 256, 256, 0, stream>>>(cnt, dinv, Nn);
    block_sum_kernel<<<nb, 256, 0, stream>>>(cnt, bsum, Nn);
    scan_partials_kernel<<<1, 256, 0, stream>>>(bsum, boff, row_ptr, nb, Nn);
    scan_write_kernel<<<nb, 256, 0, stream>>>(cnt, boff, row_ptr, cursor, Nn);
    fill_kernel<<<(E + 255) / 256, 256, 0, stream>>>(srcp, dstp, cursor, col, E);

    // ---- layer 1 ----
    {
        dim3 grid((Nn + 127) / 128, D_HID / 128);
        gemm_bf16_kernel<D_HID><<<grid, 256, 0, stream>>>(zb, w1t, x1b, Nn);
    }
    {
        int blocks = (Nn * 64 + 255) / 256;
        aggregate_kernel<D_HID, true, true><<<blocks, 256, 0, stream>>>(x1b, row_ptr, col, dinv, b1, hb, Nn);
    }

    // ---- layer 2 ----
    {
        dim3 grid((Nn + 127) / 128, D_OUT / 128);
        gemm_bf16_kernel<D_OUT><<<grid, 256, 0, stream>>>(hb, w2t, h2b, Nn);
    }
    {
        int blocks = (Nn * 64 + 255) / 256;
        aggregate_kernel<D_OUT, false, false><<<blocks, 256, 0, stream>>>(h2b, row_ptr, col, dinv, b2, out, Nn);
    }
}